// Round 9
// baseline (941.032 us; speedup 1.0000x reference)
//
#include <hip/hip_runtime.h>

// Problem constants (fixed by reference)
#define NE 8
#define TT 2048            // tokens per expert
#define KD 2048            // INPUT_SIZE  (K)
#define ND 8192            // OUTPUT_SIZE (N)
#define MT (NE * TT)       // 16384 total rows
#define NW ((size_t)NE * ND * KD)   // 134217728 weight elems
#define NX ((size_t)MT * KD)        // 33554432 input elems

typedef _Float16 f16;
typedef _Float16 f16x4 __attribute__((ext_vector_type(4)));
typedef _Float16 f16x8 __attribute__((ext_vector_type(8)));
typedef float    f32x4 __attribute__((ext_vector_type(4)));

// ---------------- K1: partial abs-sum (f64, deterministic) ----------------
__global__ void k_abs_partial(const float* __restrict__ w, double* __restrict__ part) {
    __shared__ double sred[256];
    const size_t n4 = NW / 4;
    const size_t stride = (size_t)gridDim.x * blockDim.x;
    double acc = 0.0;
    for (size_t i = (size_t)blockIdx.x * blockDim.x + threadIdx.x; i < n4; i += stride) {
        float4 v = ((const float4*)w)[i];
        acc += (double)fabsf(v.x) + (double)fabsf(v.y) + (double)fabsf(v.z) + (double)fabsf(v.w);
    }
    sred[threadIdx.x] = acc;
    __syncthreads();
    for (int s = 128; s > 0; s >>= 1) {
        if ((int)threadIdx.x < s) sred[threadIdx.x] += sred[threadIdx.x + s];
        __syncthreads();
    }
    if (threadIdx.x == 0) part[blockIdx.x] = sred[0];
}

// ---------------- K2: finalize scale ----------------
__global__ void k_finalize(const double* __restrict__ part, double* __restrict__ sc) {
    __shared__ double sred[256];
    double a = 0.0;
    for (int i = threadIdx.x; i < 2048; i += 256) a += part[i];
    sred[threadIdx.x] = a;
    __syncthreads();
    for (int s = 128; s > 0; s >>= 1) {
        if ((int)threadIdx.x < s) sred[threadIdx.x] += sred[threadIdx.x + s];
        __syncthreads();
    }
    if (threadIdx.x == 0) {
        double mean = sred[0] / (double)NW;
        double denom = mean > 1e-5 ? mean : 1e-5;
        sc[0] = 1.0 / denom;   // scale
        sc[1] = denom;         // 1/scale (output multiplier)
    }
}

// ---------------- K3: quantize w -> ternary f16 ----------------
__global__ void k_quant(const float* __restrict__ w, const double* __restrict__ sc,
                        f16* __restrict__ q) {
    const double scale = sc[0];
    const size_t n4 = NW / 4;
    const size_t stride = (size_t)gridDim.x * blockDim.x;
    for (size_t i = (size_t)blockIdx.x * blockDim.x + threadIdx.x; i < n4; i += stride) {
        float4 v = ((const float4*)w)[i];
        f16x4 o;
        o[0] = (f16)(float)fmin(fmax(rint((double)v.x * scale), -1.0), 1.0);
        o[1] = (f16)(float)fmin(fmax(rint((double)v.y * scale), -1.0), 1.0);
        o[2] = (f16)(float)fmin(fmax(rint((double)v.z * scale), -1.0), 1.0);
        o[3] = (f16)(float)fmin(fmax(rint((double)v.w * scale), -1.0), 1.0);
        ((f16x4*)q)[i] = o;
    }
}

// ---------------- K4: x f32 -> f16 ----------------
__global__ void k_xconv(const float* __restrict__ x, f16* __restrict__ xh) {
    const size_t n4 = NX / 4;
    const size_t stride = (size_t)gridDim.x * blockDim.x;
    for (size_t i = (size_t)blockIdx.x * blockDim.x + threadIdx.x; i < n4; i += stride) {
        float4 v = ((const float4*)x)[i];
        f16x4 o;
        o[0] = (f16)v.x; o[1] = (f16)v.y; o[2] = (f16)v.z; o[3] = (f16)v.w;
        ((f16x4*)xh)[i] = o;
    }
}

// ---------------- K5: grouped GEMM, 256x256x32, ring-4, read-ahead regs ---
// THE point of this round: ds_reads (tile t+1) and MFMAs (tile t) issue in the
// SAME window per wave, so the LDS port and matrix pipe run CONCURRENTLY
// instead of alternating (all prior rounds summed them -> MfmaUtil 39%).
// 8 waves (2M x 4N). Ring-4 LDS slots x 32 KiB ([A 16K | B 16K], BK=32).
// Per body i (ONE barrier):
//   stage(i+3) -> slot[(i+3)&3]          (4 gloads; overwrites b(i-1))
//   vmcnt(8)                              (b(i+1) landed: 8 newer = i+2,i+3)
//   lgkmcnt(0)                            (my R(i) reads retired, PRE-barrier
//                                          -> overwrite of b(i-1) next body is
//                                          barrier-exact race-free)
//   s_barrier ; sched_barrier
//   R(i+1): 12 ds_read_b128 (no wait)     -> frag regs buf[(i+1)&1]
//   MFMA(i): 32 mfma on frag buf[i&1]     (regs; no LDS dependency)
// gload imm stays 0 ALWAYS (nonzero shifts global AND LDS: round-4 NaN).

__device__ __forceinline__ void gload16(const void* g, void* l) {
    __builtin_amdgcn_global_load_lds(
        (const __attribute__((address_space(1))) unsigned int*)g,
        (__attribute__((address_space(3))) unsigned int*)l, 16, 0, 0);
}

#define BARR() asm volatile("s_barrier" ::: "memory")
#define SCHED0() __builtin_amdgcn_sched_barrier(0)
#define LGKM0() asm volatile("s_waitcnt lgkmcnt(0)" ::: "memory")
#define VM(N) asm volatile("s_waitcnt vmcnt(" #N ")" ::: "memory")

// 12 fragment reads: 8 A + 4 B, base VGPR + compile-time imm (<= 52224)
#define RD12(AF, BF, BPA, BPB, IMM0) do { \
  _Pragma("unroll") for (int m_ = 0; m_ < 8; ++m_) \
    AF[m_] = *(const f16x8*)((BPA) + ((IMM0) + m_ * 1024)); \
  _Pragma("unroll") for (int n_ = 0; n_ < 4; ++n_) \
    BF[n_] = *(const f16x8*)((BPB) + ((IMM0) + n_ * 1024)); \
} while (0)

#define MM32(AF, BF) do { \
  __builtin_amdgcn_s_setprio(1); \
  _Pragma("unroll") for (int m_ = 0; m_ < 8; ++m_) \
    _Pragma("unroll") for (int n_ = 0; n_ < 4; ++n_) \
      acc[m_][n_] = __builtin_amdgcn_mfma_f32_16x16x32_f16( \
          AF[m_], BF[n_], acc[m_][n_], 0, 0, 0); \
  __builtin_amdgcn_s_setprio(0); } while (0)

// stage one tile (A 16K + B 16K) into slot base SB; bump k pointers +64 B
#define STG(SB) do { \
    gload16(pA0, dstA + (SB)); \
    gload16(pA1, dstA + (SB) + 1024); \
    gload16(pB0, dstA + (SB) + 16384); \
    gload16(pB1, dstA + (SB) + 17408); \
    pA0 += 64; pA1 += 64; pB0 += 64; pB1 += 64; \
    asm volatile("" : "+v"(pA0), "+v"(pA1), "+v"(pB0), "+v"(pB1)); \
} while (0)

// body: stage slot SSB, read tile from (BPA,BPB,RIMM) into (AFW,BFW),
// MFMA on (AFR,BFR)
#define BODY(SSB, BPA, BPB, RIMM, AFW, BFW, AFR, BFR) do { \
    STG(SSB); \
    VM(8); LGKM0(); BARR(); SCHED0(); \
    RD12(AFW, BFW, BPA, BPB, RIMM); SCHED0(); \
    MM32(AFR, BFR); \
} while (0)

__global__ __launch_bounds__(512, 2)
void k_gemm(const f16* __restrict__ xh, const f16* __restrict__ qh,
            const double* __restrict__ sc, float* __restrict__ out) {
    __shared__ char lds[4 * 32768];   // ring-4, 128 KiB

    const int lane = (int)threadIdx.x & 63;
    const int wid  = (int)threadIdx.x >> 6;   // 0..7
    const int wr   = wid >> 2;                 // 0..1  (M strip of 128)
    const int wc   = wid & 3;                  // 0..3  (N strip of 64)
    const int li   = lane & 15;
    const int sl   = lane >> 4;                // k-slot 0..3

    // XCD-aware swizzle + round-6 block mapping (FETCH ~0.4 GB proven)
    const int wg = ((int)blockIdx.x & 7) * 256 + ((int)blockIdx.x >> 3);
    const int e  = wg >> 8;
    const int u  = wg & 255;
    const int mt = (u >> 1) & 7;
    const int nt = (((u >> 4) << 1) | (u & 1));

    const f16* Ab = xh + ((size_t)e * TT + (size_t)mt * 256) * KD;
    const f16* Bb = qh + ((size_t)e * ND + (size_t)nt * 256) * KD;
    float*     Cb = out + ((size_t)e * TT + (size_t)mt * 256) * ND + (size_t)nt * 256;

    const float sfac = (float)sc[1];
    asm volatile("s_waitcnt vmcnt(0)" ::: "memory");

    // read bases (verified swizzle: phys slot = sl ^ (li&3) ^ ((li>>2)&3))
    const int pA = (sl ^ (lane & 3) ^ ((lane >> 2) & 3)) & 3;
    const char* aRlo = (const char*)lds + ((wr * 128 + li) << 6) + (pA << 4);
    const char* bRlo = (const char*)lds + 16384 + ((wc * 64 + li) << 6) + (pA << 4);
    const char* aRhi = aRlo + 65536;
    const char* bRhi = bRlo + 65536;

    // staging: 32-row chunk per wave per region; inverse-swizzled source
    const int lslot = (lane & 3) ^ ((lane >> 2) & 3) ^ ((lane >> 4) & 3);
    char* dstA = (char*)lds + wid * 2048;
    const int srow0 = wid * 32 + (lane >> 2);        // rows 0..255 (g=0)
    const int srow1 = srow0 + 16;                    // g=1
    const char* pA0 = (const char*)(Ab + (size_t)srow0 * KD + lslot * 8);
    const char* pA1 = (const char*)(Ab + (size_t)srow1 * KD + lslot * 8);
    const char* pB0 = (const char*)(Bb + (size_t)srow0 * KD + lslot * 8);
    const char* pB1 = (const char*)(Bb + (size_t)srow1 * KD + lslot * 8);

    f32x4 acc[8][4];
#pragma unroll
    for (int m = 0; m < 8; ++m)
#pragma unroll
        for (int n = 0; n < 4; ++n) acc[m][n] = (f32x4){0.f, 0.f, 0.f, 0.f};

    f16x8 af0[8], bf0[4], af1[8], bf1[4];

    // prologue: stage tiles 0,1,2 into slots 0,1,2; read R(0) from slot0
    STG(0);
    STG(32768);
    STG(65536);
    VM(8);          // tile 0 landed
    BARR(); SCHED0();
    RD12(af0, bf0, aRlo, bRlo, 0);

    // bodies 0..59 (4 per iteration: slots/parity period aligns)
#pragma unroll 1
    for (int j = 0; j < 15; ++j) {
        BODY(98304, aRlo, bRlo, 32768, af1, bf1, af0, bf0);  // i=4j+0: stage s3, R s1
        BODY(0,     aRhi, bRhi, 0,     af0, bf0, af1, bf1);  // i=4j+1: stage s0, R s2
        BODY(32768, aRhi, bRhi, 32768, af1, bf1, af0, bf0);  // i=4j+2: stage s1, R s3
        BODY(65536, aRlo, bRlo, 0,     af0, bf0, af1, bf1);  // i=4j+3: stage s2, R s0
    }
    // body 60: full (stage tile 63 -> slot3)
    BODY(98304, aRlo, bRlo, 32768, af1, bf1, af0, bf0);
    // body 61: no stage; b(62) landed after VM(4)
    VM(4); LGKM0(); BARR(); SCHED0();
    RD12(af0, bf0, aRhi, bRhi, 0); SCHED0();
    MM32(af1, bf1);
    // body 62: no stage; b(63) landed after VM(0)
    VM(0); LGKM0(); BARR(); SCHED0();
    RD12(af1, bf1, aRhi, bRhi, 32768); SCHED0();
    MM32(af0, bf0);
    // body 63
    LGKM0(); SCHED0();
    MM32(af1, bf1);

    // ---- epilogue: scale by 1/scale, f32 store (verified layout) ----
#pragma unroll
    for (int m = 0; m < 8; ++m)
#pragma unroll
        for (int n = 0; n < 4; ++n)
#pragma unroll
            for (int r4 = 0; r4 < 4; ++r4) {
                const int row = wr * 128 + m * 16 + sl * 4 + r4;
                const int col = wc * 64 + n * 16 + li;
                Cb[(size_t)row * ND + col] = acc[m][n][r4] * sfac;
            }
}

// ---------------- fallback (only if ws too small): f32 tiled, on-the-fly quant ----------------
__global__ void k_fallback(const float* __restrict__ x, const float* __restrict__ w,
                           const double* __restrict__ sc, float* __restrict__ out) {
    const int row0 = blockIdx.x * 16;
    const int col0 = blockIdx.y * 16;
    const int e = row0 / TT;
    __shared__ float xs[16][17];
    __shared__ float wq[16][17];
    const double scale = sc[0];
    const float s = (float)sc[1];
    const int tx = threadIdx.x, ty = threadIdx.y;
    const float* wbase = w + ((size_t)e * ND + col0) * KD;
    float acc = 0.f;
    for (int k0 = 0; k0 < KD; k0 += 16) {
        xs[ty][tx] = x[(size_t)(row0 + ty) * KD + k0 + tx];
        const float wv = wbase[(size_t)ty * KD + k0 + tx];
        wq[ty][tx] = (float)fmin(fmax(rint((double)wv * scale), -1.0), 1.0);
        __syncthreads();
#pragma unroll
        for (int kk = 0; kk < 16; ++kk) acc += xs[ty][kk] * wq[tx][kk];
        __syncthreads();
    }
    out[(size_t)(row0 + ty) * ND + col0 + tx] = acc * s;
}

// ---------------- launch ----------------
extern "C" void kernel_launch(void* const* d_in, const int* in_sizes, int n_in,
                              void* d_out, int out_size, void* d_ws, size_t ws_size,
                              hipStream_t stream) {
    const float* x = (const float*)d_in[0];
    const float* w = (const float*)d_in[1];
    float* out = (float*)d_out;

    double* part = (double*)d_ws;                       // 2048 * 8 B
    double* sc   = (double*)((char*)d_ws + 16384);      // [0]=scale, [1]=1/scale

    const size_t need = 65536 + NX * 2 + NW * 2;        // ~320 MiB

    hipLaunchKernelGGL(k_abs_partial, dim3(2048), dim3(256), 0, stream, w, part);
    hipLaunchKernelGGL(k_finalize,   dim3(1),    dim3(256), 0, stream, part, sc);

    if (ws_size >= need) {
        f16* xh = (f16*)((char*)d_ws + 65536);
        f16* qh = (f16*)((char*)d_ws + 65536 + NX * 2);
        hipLaunchKernelGGL(k_quant, dim3(2048), dim3(256), 0, stream, w, sc, qh);
        hipLaunchKernelGGL(k_xconv, dim3(2048), dim3(256), 0, stream, x, xh);
        hipLaunchKernelGGL(k_gemm,  dim3(NE * (TT / 256) * (ND / 256)), dim3(512), 0, stream,
                           xh, qh, sc, out);
    } else {
        dim3 grid(MT / 16, ND / 16);
        hipLaunchKernelGGL(k_fallback, grid, dim3(16, 16), 0, stream, x, w, sc, out);
    }
}